// Round 23
// baseline (537.316 us; speedup 1.0000x reference)
//
#include <hip/hip_runtime.h>
#include <math.h>

namespace {

constexpr int Bn = 4;
constexpr int H0 = 256, W0 = 448;
constexpr int H1 = 128, W1 = 224;
constexpr int H2 = 64,  W2 = 112;
constexpr int HW0 = H0 * W0;
constexpr int HW1 = H1 * W1;
constexpr int HW2 = H2 * W2;
constexpr int IRRCAP = 8192;
constexpr int OVCAP  = 4096;

// np.linspace(-1+1/n, 1-1/n, n, dtype=f32) bit path (backwarp side; validated).
__device__ inline float lin_ac_f32(int i, int n) {
    if (i == n - 1) return (float)(1.0 - 1.0 / (double)n);
    double start = -1.0 + 1.0 / (double)n;
    double step  = (2.0 - 2.0 / (double)n) / (double)(n - 1);
    return (float)(start + (double)i * step);
}

// jax-f32 linspace bit path + endpoint forcing (validated round 6).
__device__ inline void ac32_iota(int i, int n_in, int n_out, float delta,
                                 int& i0, int& i1, float& fr) {
    float v = (i == n_out - 1) ? (float)(n_in - 1) : __fmul_rn(delta, (float)i);
    float f0 = floorf(v);
    i0 = (int)f0;
    i1 = min(i0 + 1, n_in - 1);
    fr = __fsub_rn(v, f0);
}

// Unfused pinned f32 bilinear (validated round 6).
__device__ inline float bilerp32(const float* __restrict__ s, int Win,
                                 int y0, int y1, int x0, int x1,
                                 float wy, float wx) {
    float a = s[y0 * Win + x0], b = s[y1 * Win + x0];
    float c = s[y0 * Win + x1], d = s[y1 * Win + x1];
    float omwy = __fsub_rn(1.0f, wy), omwx = __fsub_rn(1.0f, wx);
    float r0 = __fadd_rn(__fmul_rn(a, omwy), __fmul_rn(b, wy));
    float r1 = __fadd_rn(__fmul_rn(c, omwy), __fmul_rn(d, wy));
    return __fadd_rn(__fmul_rn(r0, omwx), __fmul_rn(r1, wx));
}

// chunked XCD swizzle (grid divisible by 8)
__device__ inline int swz_block(int bid, int nblk) {
    int cpx = nblk >> 3;
    return (bid & 7) * cpx + (bid >> 3);
}

// ---------------------------------------------------------------------------
// Tap geometry — EXACT round-6/R16 bit paths (validated).
// ---------------------------------------------------------------------------
template<int LVL, int D>
struct Geo {
    int   tx[4], ty[4];
    float tw[4];
    float gx, gy;
    bool  reg;
    int   ry0, ry1, rx0, rx1;
    float wy, wx;
};

template<int LVL, int D>
__device__ inline Geo<LVL, D> geom(int x, int y, int b, int h, int w,
                                   const float* __restrict__ flow,
                                   float scale, float dly, float dlx) {
    Geo<LVL, D> g;
    float gx, gy, x0f, y0f, x1f, y1f;
    if constexpr (LVL == 0) {
        const float* fb = flow + (size_t)b * 2 * HW0;
        float fx = 0.5f * fb[y * W0 + x];
        float fy = 0.5f * fb[(size_t)HW0 + y * W0 + x];
        gx = (float)x + fx;
        gy = (float)y + fy;
        x0f = floorf(gx); y0f = floorf(gy);
        x1f = x0f + 1.f;  y1f = y0f + 1.f;
        g.tw[0] = (x1f - gx) * (y1f - gy); g.tw[1] = (gx - x0f) * (y1f - gy);
        g.tw[2] = (x1f - gx) * (gy - y0f); g.tw[3] = (gx - x0f) * (gy - y0f);
    } else {
        ac32_iota(y, H0, h, dly, g.ry0, g.ry1, g.wy);
        ac32_iota(x, W0, w, dlx, g.rx0, g.rx1, g.wx);
        const float* fB = flow + (size_t)b * 2 * HW0;
        float fx = __fmul_rn(bilerp32(fB, W0, g.ry0, g.ry1, g.rx0, g.rx1, g.wy, g.wx), scale);
        float fy = __fmul_rn(bilerp32(fB + (size_t)HW0, W0, g.ry0, g.ry1, g.rx0, g.rx1, g.wy, g.wx), scale);
        gx = __fadd_rn((float)x, fx);
        gy = __fadd_rn((float)y, fy);
        x0f = floorf(gx); y0f = floorf(gy);
        x1f = __fadd_rn(x0f, 1.0f); y1f = __fadd_rn(y0f, 1.0f);
        float dx0 = __fsub_rn(x1f, gx), dx1 = __fsub_rn(gx, x0f);
        float dy0 = __fsub_rn(y1f, gy), dy1 = __fsub_rn(gy, y0f);
        g.tw[0] = __fmul_rn(dx0, dy0); g.tw[1] = __fmul_rn(dx1, dy0);
        g.tw[2] = __fmul_rn(dx0, dy1); g.tw[3] = __fmul_rn(dx1, dy1);
    }
    g.gx = gx; g.gy = gy;
    int x0 = (int)x0f, y0 = (int)y0f;
    g.tx[0] = x0;     g.tx[1] = x0 + 1; g.tx[2] = x0;     g.tx[3] = x0 + 1;
    g.ty[0] = y0;     g.ty[1] = y0;     g.ty[2] = y0 + 1; g.ty[3] = y0 + 1;
    g.reg = (x0 >= x - D) && (x0 + 1 <= x + D) && (y0 >= y - D) && (y0 + 1 <= y + D);
    return g;
}

// ---------------------------------------------------------------------------
// Metric (both dirs) FUSED with L0 irregular detection (validated R19).
// ---------------------------------------------------------------------------
__global__ __launch_bounds__(256) void metric2irr0_kernel(
        const float* __restrict__ img1, const float* __restrict__ img2,
        const float* __restrict__ fl12, const float* __restrict__ fl21,
        float* __restrict__ m12, float* __restrict__ m21,
        int* __restrict__ irrcnt, int* __restrict__ irrlist) {
    int idx = blockIdx.x * 256 + threadIdx.x;
    int total = 2 * Bn * HW0;
    if (idx >= total) return;
    int dir = idx / (Bn * HW0);
    int sub = idx % (Bn * HW0);
    const float* imgA = dir ? img2 : img1;
    const float* imgB = dir ? img1 : img2;
    const float* flow = dir ? fl21 : fl12;
    float* mout = dir ? m21 : m12;

    int x = sub % W0;
    int y = (sub / W0) % H0;
    int b = sub / HW0;

    const float* fb = flow + (size_t)b * 2 * HW0;
    float fx = fb[y * W0 + x];
    float fy = fb[(size_t)HW0 + y * W0 + x];

    const float sxc = (float)(2.0 / (double)(W0 - 1));
    const float syc = (float)(2.0 / (double)(H0 - 1));
    float ggx = __fadd_rn(lin_ac_f32(x, W0), __fmul_rn(fx, sxc));
    float ggy = __fadd_rn(lin_ac_f32(y, H0), __fmul_rn(fy, syc));
    float px = __fmul_rn(__fmul_rn(__fadd_rn(ggx, 1.0f), 0.5f), (float)(W0 - 1));
    float py = __fmul_rn(__fmul_rn(__fadd_rn(ggy, 1.0f), 0.5f), (float)(H0 - 1));

    float x0f = floorf(px), y0f = floorf(py);
    float x1f = x0f + 1.0f, y1f = y0f + 1.0f;
    int x0 = (int)x0f, y0 = (int)y0f, x1 = (int)x1f, y1 = (int)y1f;

    float tw[4] = { (x1f - px) * (y1f - py), (px - x0f) * (y1f - py),
                    (x1f - px) * (py - y0f), (px - x0f) * (py - y0f) };
    int tx[4] = { x0, x1, x0, x1 };
    int ty[4] = { y0, y0, y1, y1 };

    const float* ib = imgB + (size_t)b * 3 * HW0;
    float acc0 = 0.f, acc1 = 0.f, acc2 = 0.f;
#pragma unroll
    for (int t = 0; t < 4; ++t) {
        bool valid = (tx[t] >= 0) && (tx[t] < W0) && (ty[t] >= 0) && (ty[t] < H0);
        int xc = min(max(tx[t], 0), W0 - 1);
        int yc = min(max(ty[t], 0), H0 - 1);
        float ww = valid ? tw[t] : 0.f;
        int off = yc * W0 + xc;
        acc0 += ib[off] * ww;
        acc1 += ib[(size_t)HW0 + off] * ww;
        acc2 += ib[(size_t)2 * HW0 + off] * ww;
    }
    const float* ia = imgA + (size_t)b * 3 * HW0;
    int off = y * W0 + x;
    float m = (fabsf(ia[off] - acc0) +
               fabsf(ia[(size_t)HW0 + off] - acc1) +
               fabsf(ia[(size_t)2 * HW0 + off] - acc2)) * (1.f / 3.f);
    mout[(size_t)b * HW0 + off] = m;

    // ---- L0 irregular detection (D=16 predicate, matches gather) ----
    float fxh = 0.5f * fx;
    float fyh = 0.5f * fy;
    float sgx = (float)x + fxh;
    float sgy = (float)y + fyh;
    int sx0 = (int)floorf(sgx);
    int sy0 = (int)floorf(sgy);
    bool reg = (sx0 >= x - 16) && (sx0 + 1 <= x + 16) &&
               (sy0 >= y - 16) && (sy0 + 1 <= y + 16);
    if (reg) return;
    bool any = (sx0 >= -1) && (sx0 <= W0 - 1) && (sy0 >= -1) && (sy0 <= H0 - 1);
    if (!any) return;
    int pos = atomicAdd(irrcnt, 1);
    if (pos < IRRCAP) irrlist[pos] = (dir << 20) | (b << 18) | (y * W0 + x);
}

// ---------------------------------------------------------------------------
// Irregular detection for L1+L2 (one launch, segmented; validated R19).
// ---------------------------------------------------------------------------
__global__ __launch_bounds__(256) void irr12_kernel(
        const float* __restrict__ fl12, const float* __restrict__ fl21,
        int* __restrict__ irrcnt1, int* __restrict__ irrlist1,
        int* __restrict__ irrcnt2, int* __restrict__ irrlist2,
        float dy1v, float dx1v, float dy2v, float dx2v) {
    int idx = blockIdx.x * 256 + threadIdx.x;
    const int n1 = 2 * Bn * HW1;
    const int n2 = 2 * Bn * HW2;
    if (idx >= n1 + n2) return;
    int lvl2 = (idx >= n1);
    int sub2 = lvl2 ? (idx - n1) : idx;
    int h = lvl2 ? H2 : H1, w = lvl2 ? W2 : W1;
    float scale = lvl2 ? 0.125f : 0.25f;
    float dly = lvl2 ? dy2v : dy1v, dlx = lvl2 ? dx2v : dx1v;
    int* cnt = lvl2 ? irrcnt2 : irrcnt1;
    int* list = lvl2 ? irrlist2 : irrlist1;

    int hw = h * w;
    int dir = sub2 / (Bn * hw);
    int sub = sub2 % (Bn * hw);
    const float* flow = dir ? fl21 : fl12;
    int x = sub % w, y = (sub / w) % h, b = sub / hw;

    Geo<1, 8> g = geom<1, 8>(x, y, b, h, w, flow, scale, dly, dlx);
    if (g.reg) return;
    bool any = false;
#pragma unroll
    for (int t = 0; t < 4; ++t)
        any = any || ((g.tx[t] >= 0) && (g.tx[t] < w) && (g.ty[t] >= 0) && (g.ty[t] < h));
    if (!any) return;
    int pos = atomicAdd(cnt, 1);
    if (pos < IRRCAP) list[pos] = (dir << 20) | (b << 18) | (y * w + x);
}

// ---------------------------------------------------------------------------
// Transpose NCHW->NHWC (validated R21): compile-time CH, float4 reads,
// SPAN=64, padded LDS stride.
// ---------------------------------------------------------------------------
constexpr int TSPAN = 64;

template<int CH, int C0, int C1>
__device__ inline void tbody(const float* __restrict__ s0,
                             const float* __restrict__ s1,
                             float* __restrict__ dst, int HW, int gp,
                             float* __restrict__ lds) {
    constexpr int S = CH + 1;
    constexpr int PV = TSPAN / 4;
    constexpr int CT = C0 + C1;
    int b = gp / HW, p0 = gp % HW;
    int tid = threadIdx.x;

#pragma unroll 4
    for (int i = tid; i < CH * PV; i += 256) {
        int c = i / PV;
        int pv = (i % PV) * 4;
        float4 v = { 0.f, 0.f, 0.f, 0.f };
        if (c < C0)
            v = *(const float4*)(s0 + ((size_t)b * C0 + c) * HW + p0 + pv);
        else if (c < CT)
            v = *(const float4*)(s1 + ((size_t)b * C1 + (c - C0)) * HW + p0 + pv);
        lds[(pv + 0) * S + c] = v.x;
        lds[(pv + 1) * S + c] = v.y;
        lds[(pv + 2) * S + c] = v.z;
        lds[(pv + 3) * S + c] = v.w;
    }
    __syncthreads();

    constexpr int N4 = TSPAN * CH / 4;
    float4* d4 = (float4*)(dst + (size_t)gp * CH);
#pragma unroll 4
    for (int i = tid; i < N4; i += 256) {
        int j = i * 4;
        int p = j / CH, c = j % CH;
        float4 q = { lds[p * S + c], lds[p * S + c + 1],
                     lds[p * S + c + 2], lds[p * S + c + 3] };
        d4[i] = q;
    }
}

struct TSegs {
    const float* s0[6];
    const float* s1[6];
    float*       d[6];
    int start[7];
};

__global__ __launch_bounds__(256) void transpose_all_kernel(TSegs ts) {
    __shared__ float lds[TSPAN * 97];
    int bid = blockIdx.x;
    int k = 0;
#pragma unroll
    for (int i = 1; i < 6; ++i) if (bid >= ts.start[i]) k = i;
    int gp = (bid - ts.start[k]) * TSPAN;
    switch (k) {
        case 0: tbody<36, 3, 32>(ts.s0[0], ts.s1[0], ts.d[0], HW0, gp, lds); break;
        case 1: tbody<36, 3, 32>(ts.s0[1], ts.s1[1], ts.d[1], HW0, gp, lds); break;
        case 2: tbody<64, 64, 0>(ts.s0[2], ts.s1[2], ts.d[2], HW1, gp, lds); break;
        case 3: tbody<64, 64, 0>(ts.s0[3], ts.s1[3], ts.d[3], HW1, gp, lds); break;
        case 4: tbody<96, 96, 0>(ts.s0[4], ts.s1[4], ts.d[4], HW2, gp, lds); break;
        case 5: tbody<96, 96, 0>(ts.s0[5], ts.s1[5], ts.d[5], HW2, gp, lds); break;
    }
}

// ---------------------------------------------------------------------------
// Full-recompute gather (overflow path only; rare). Validated R16 body.
// ---------------------------------------------------------------------------
template<int LVL, int D, int H, int W, int CBT4, int NVM>
__device__ inline void gather_one(int sidx, int b, int px, int py, int voff, int nv,
        const float* __restrict__ flow, const float* __restrict__ met, float a,
        float scale, float dly, float dlx, const float4* __restrict__ nhwc,
        float (&ax)[NVM], float (&ay)[NVM], float (&az)[NVM], float (&aw)[NVM],
        float& wacc) {
    int sx = sidx % W, sy = sidx / W;
    Geo<LVL, D> g = geom<LVL, D>(sx, sy, b, H, W, flow, scale, dly, dlx);
    int ddx = px - g.tx[0], ddy = py - g.ty[0];
    if (((unsigned)ddx > 1u) || ((unsigned)ddy > 1u)) return;
    int t = ddy * 2 + ddx;
    float wgt;
    if constexpr (LVL == 0) wgt = expf(a * met[(size_t)b * HW0 + sy * W0 + sx]);
    else {
        float m = bilerp32(met + (size_t)b * HW0, W0, g.ry0, g.ry1, g.rx0, g.rx1, g.wy, g.wx);
        wgt = expf(__fmul_rn(a, m));
    }
    float tw = (t == 0) ? g.tw[0] : (t == 1) ? g.tw[1] : (t == 2) ? g.tw[2] : g.tw[3];
    float twv = (LVL == 0) ? tw * wgt : __fmul_rn(wgt, tw);
    wacc += twv;
    const float4* vp = nhwc + ((size_t)b * (H * W) + sidx) * CBT4 + voff;
#pragma unroll
    for (int vi = 0; vi < NVM; ++vi) {
        if (vi >= nv) break;
        float4 q = vp[vi];
        if constexpr (LVL == 0) {
            ax[vi] += q.x * twv; ay[vi] += q.y * twv;
            az[vi] += q.z * twv; aw[vi] += q.w * twv;
        } else {
            ax[vi] += __fmul_rn(__fmul_rn(q.x, wgt), tw);
            ay[vi] += __fmul_rn(__fmul_rn(q.y, wgt), tw);
            az[vi] += __fmul_rn(__fmul_rn(q.z, wgt), tw);
            aw[vi] += __fmul_rn(__fmul_rn(q.w, wgt), tw);
        }
    }
}

// ---------------------------------------------------------------------------
// Gather (validated R22 structure). R23 deltas: KBT lowered (L0 6->5,
// L1/L2 10->8) to raise occupancy (LDS 56.3->47.1KB: 2->3 blocks/CU at L0;
// 47.6->38.4KB: 3->4 at L1/L2); overflow-merge reads use PLAIN loads (own
// entries written atomically pre-barrier; tag filter discards others; first
// touch post-barrier so no stale L1 line).
// ---------------------------------------------------------------------------
template<int LVL, int CREAL, int CBT4, int NV0, int NV1, int D, int TH, int TW,
         int KBT, int H, int W>
__global__ __launch_bounds__(512) void gather_kernel(
        const float4* __restrict__ nhwcA, const float4* __restrict__ nhwcB,
        const float* __restrict__ fl12, const float* __restrict__ fl21,
        const float* __restrict__ m12, const float* __restrict__ m21,
        const float* __restrict__ alphap,
        const int* __restrict__ irrn_p, const int* __restrict__ irrlist,
        int* __restrict__ ovn_p, int* __restrict__ ovlist,
        float* __restrict__ outp, int Cout, int cbase0, int cbase1,
        float scale, float dly, float dlx) {
    constexpr int NPIX = TH * TW;
    constexpr bool FULL = (NPIX == 512);
    constexpr int NBX = TW + 1, NB = NBX * (TH + 1);
    constexpr int NVM = FULL ? CBT4 : ((NV0 > NV1) ? NV0 : NV1);
    constexpr int HW_ = H * W;
    __shared__ int   bcnt[NB];
    __shared__ int   bsidx[NB * KBT];
    __shared__ float bgx[NB * KBT], bgy[NB * KBT], bwgt[NB * KBT];
    __shared__ int s_irrn, s_ovn;

    const int tilesX = W / TW, tilesY = H / TH;
    int s = swz_block(blockIdx.x, gridDim.x);
    int tpb = tilesX * tilesY;
    int dir = s / (Bn * tpb);
    int rem = s % (Bn * tpb);
    int b = rem / tpb, r = rem % tpb;
    int ty0 = (r / tilesX) * TH, tx0 = (r % tilesX) * TW;
    int tid = threadIdx.x;

    const float* flow = dir ? fl21 : fl12;
    const float* met  = dir ? m21 : m12;
    const float4* nhwc = dir ? nhwcB : nhwcA;
    int cbase = dir ? cbase1 : cbase0;

    for (int i = tid; i < NB; i += 512) bcnt[i] = 0;
    if (tid == 0) s_irrn = irrn_p[0];
    __syncthreads();

    float a = alphap[0];

    // ---- phase 1a: window scan; bin by destination cell ----
    constexpr int WH = TH + 2 * D, WW2 = TW + 2 * D;
    int wy0 = ty0 - D, wx0 = tx0 - D;
    for (int i = tid; i < WH * WW2; i += 512) {
        int sy = wy0 + i / WW2, sx = wx0 + i % WW2;
        if (sy < 0 || sy >= H || sx < 0 || sx >= W) continue;
        Geo<LVL, D> g = geom<LVL, D>(sx, sy, b, H, W, flow, scale, dly, dlx);
        if (!g.reg) continue;
        int cx = g.tx[0], cy = g.ty[0];
        if (cx < tx0 - 1 || cx > tx0 + TW - 1 || cy < ty0 - 1 || cy > ty0 + TH - 1) continue;
        float wgt;
        if constexpr (LVL == 0) wgt = expf(a * met[(size_t)b * HW0 + sy * W0 + sx]);
        else {
            float m = bilerp32(met + (size_t)b * HW0, W0, g.ry0, g.ry1, g.rx0, g.rx1, g.wy, g.wx);
            wgt = expf(__fmul_rn(a, m));
        }
        int bin = (cy - (ty0 - 1)) * NBX + (cx - (tx0 - 1));
        int pos = atomicAdd(&bcnt[bin], 1);
        int sidx = sy * W + sx;
        if (pos < KBT) {
            int e = bin * KBT + pos;
            bsidx[e] = sidx; bgx[e] = g.gx; bgy[e] = g.gy; bwgt[e] = wgt;
        } else {
            int p2 = atomicAdd(ovn_p, 1);
            if (p2 < OVCAP) { atomicExch(&ovlist[2 * p2], s); atomicExch(&ovlist[2 * p2 + 1], sidx); }
        }
    }
    // ---- phase 1b: irregular sources (dir+batch filtered) ----
    int ni = min(s_irrn, IRRCAP);
    for (int i = tid; i < ni; i += 512) {
        int e0 = irrlist[i];
        if ((e0 >> 20) != dir) continue;
        if (((e0 >> 18) & 3) != b) continue;
        int sidx = e0 & ((1 << 18) - 1);
        int sx = sidx % W, sy = sidx / W;
        Geo<LVL, D> g = geom<LVL, D>(sx, sy, b, H, W, flow, scale, dly, dlx);
        int cx = g.tx[0], cy = g.ty[0];
        if (cx < tx0 - 1 || cx > tx0 + TW - 1 || cy < ty0 - 1 || cy > ty0 + TH - 1) continue;
        float wgt;
        if constexpr (LVL == 0) wgt = expf(a * met[(size_t)b * HW0 + sy * W0 + sx]);
        else {
            float m = bilerp32(met + (size_t)b * HW0, W0, g.ry0, g.ry1, g.rx0, g.rx1, g.wy, g.wx);
            wgt = expf(__fmul_rn(a, m));
        }
        int bin = (cy - (ty0 - 1)) * NBX + (cx - (tx0 - 1));
        int pos = atomicAdd(&bcnt[bin], 1);
        if (pos < KBT) {
            int e = bin * KBT + pos;
            bsidx[e] = sidx; bgx[e] = g.gx; bgy[e] = g.gy; bwgt[e] = wgt;
        } else {
            int p2 = atomicAdd(ovn_p, 1);
            if (p2 < OVCAP) { atomicExch(&ovlist[2 * p2], s); atomicExch(&ovlist[2 * p2 + 1], sidx); }
        }
    }
    __syncthreads();
    if (tid == 0) s_ovn = atomicAdd(ovn_p, 0);
    __syncthreads();

    // ---- phase 2: register gather ----
    int pixel, voff, nv;
    if constexpr (FULL) {
        pixel = tid; voff = 0; nv = CBT4;
    } else {
        pixel = tid & 255;
        int half = tid >> 8;
        voff = half ? NV0 : 0;
        nv = half ? NV1 : NV0;
    }
    int px = tx0 + (pixel % TW), py = ty0 + (pixel / TW);
    const float4* nbp = nhwc + (size_t)b * HW_ * CBT4 + voff;
    float ax[NVM], ay[NVM], az[NVM], aw[NVM];
#pragma unroll
    for (int vi = 0; vi < NVM; ++vi) { ax[vi] = 0.f; ay[vi] = 0.f; az[vi] = 0.f; aw[vi] = 0.f; }
    float wacc = 0.f;

#pragma unroll
    for (int cyi = 0; cyi < 2; ++cyi)
#pragma unroll
    for (int cxi = 0; cxi < 2; ++cxi) {
        const int t = (1 - cyi) * 2 + (1 - cxi);
        int lc = (py - ty0 + cyi) * NBX + (px - tx0 + cxi);
        int n = min(bcnt[lc], KBT);
        for (int j = 0; j < n; ++j) {
            int e = lc * KBT + j;
            float gx = bgx[e], gy = bgy[e], wgt = bwgt[e];
            float x0f = floorf(gx), y0f = floorf(gy);
            float tw;
            if constexpr (LVL == 0) {
                float x1f = x0f + 1.f, y1f = y0f + 1.f;
                tw = (t == 0) ? (x1f - gx) * (y1f - gy)
                   : (t == 1) ? (gx - x0f) * (y1f - gy)
                   : (t == 2) ? (x1f - gx) * (gy - y0f)
                              : (gx - x0f) * (gy - y0f);
            } else {
                float x1f = __fadd_rn(x0f, 1.0f), y1f = __fadd_rn(y0f, 1.0f);
                float dx0 = __fsub_rn(x1f, gx), dx1 = __fsub_rn(gx, x0f);
                float dy0 = __fsub_rn(y1f, gy), dy1 = __fsub_rn(gy, y0f);
                tw = (t == 0) ? __fmul_rn(dx0, dy0)
                   : (t == 1) ? __fmul_rn(dx1, dy0)
                   : (t == 2) ? __fmul_rn(dx0, dy1)
                              : __fmul_rn(dx1, dy1);
            }
            const float4* vp = nbp + (size_t)bsidx[e] * CBT4;
            if constexpr (LVL == 0) {
                float twv = tw * wgt;
                wacc += twv;
#pragma unroll
                for (int vi = 0; vi < NVM; ++vi) {
                    if (vi >= nv) break;
                    float4 q = vp[vi];
                    ax[vi] += q.x * twv; ay[vi] += q.y * twv;
                    az[vi] += q.z * twv; aw[vi] += q.w * twv;
                }
            } else {
                wacc += __fmul_rn(wgt, tw);
#pragma unroll
                for (int vi = 0; vi < NVM; ++vi) {
                    if (vi >= nv) break;
                    float4 q = vp[vi];
                    ax[vi] += __fmul_rn(__fmul_rn(q.x, wgt), tw);
                    ay[vi] += __fmul_rn(__fmul_rn(q.y, wgt), tw);
                    az[vi] += __fmul_rn(__fmul_rn(q.z, wgt), tw);
                    aw[vi] += __fmul_rn(__fmul_rn(q.w, wgt), tw);
                }
            }
        }
    }
    // overflow entries (own-block tag filter; plain loads are safe: own
    // entries were atomically written pre-barrier, first touch post-barrier)
    int novr = min(s_ovn, OVCAP);
    for (int j = 0; j < novr; ++j) {
        int key = ((const volatile int*)ovlist)[2 * j];
        if (key != s) continue;
        int sidx = ((const volatile int*)ovlist)[2 * j + 1];
        gather_one<LVL, D, H, W, CBT4, NVM>(sidx, b, px, py, voff, nv,
            flow, met, a, scale, dly, dlx, nhwc, ax, ay, az, aw, wacc);
    }

    float denom = wacc + 1e-7f;
    size_t obase = ((size_t)b * Cout + cbase) * HW_ + (py * W + px);
#pragma unroll
    for (int vi = 0; vi < NVM; ++vi) {
        if (vi >= nv) break;
        int c0 = (voff + vi) * 4;
        if (c0 + 0 < CREAL) outp[obase + (size_t)(c0 + 0) * HW_] = ax[vi] / denom;
        if (c0 + 1 < CREAL) outp[obase + (size_t)(c0 + 1) * HW_] = ay[vi] / denom;
        if (c0 + 2 < CREAL) outp[obase + (size_t)(c0 + 2) * HW_] = az[vi] / denom;
        if (c0 + 3 < CREAL) outp[obase + (size_t)(c0 + 3) * HW_] = aw[vi] / denom;
    }
}

inline int nblk(long long n) { return (int)((n + 255) / 256); }

} // namespace

extern "C" void kernel_launch(void* const* d_in, const int* in_sizes, int n_in,
                              void* d_out, int out_size, void* d_ws, size_t ws_size,
                              hipStream_t stream) {
    const float* img1 = (const float*)d_in[0];
    const float* img2 = (const float*)d_in[1];
    const float* f1_1 = (const float*)d_in[2];
    const float* f1_2 = (const float*)d_in[3];
    const float* f1_3 = (const float*)d_in[4];
    const float* f2_1 = (const float*)d_in[5];
    const float* f2_2 = (const float*)d_in[6];
    const float* f2_3 = (const float*)d_in[7];
    const float* fl12 = (const float*)d_in[8];
    const float* fl21 = (const float*)d_in[9];
    const float* alpha = (const float*)d_in[10];
    float* out = (float*)d_out;

    const float dy1 = (float)(H0 - 1) / (float)(H1 - 1);
    const float dx1 = (float)(W0 - 1) / (float)(W1 - 1);
    const float dy2 = (float)(H0 - 1) / (float)(H2 - 1);
    const float dx2 = (float)(W0 - 1) / (float)(W2 - 1);

    // ---- workspace layout (NHWC buffers first, 16B-aligned) ----
    float* ws = (float*)d_ws;
    size_t o = 0;
    float* nh0a = ws + o; o += (size_t)Bn * HW0 * 36;
    float* nh0b = ws + o; o += (size_t)Bn * HW0 * 36;
    float* nh1a = ws + o; o += (size_t)Bn * HW1 * 64;
    float* nh1b = ws + o; o += (size_t)Bn * HW1 * 64;
    float* nh2a = ws + o; o += (size_t)Bn * HW2 * 96;
    float* nh2b = ws + o; o += (size_t)Bn * HW2 * 96;
    float* m12  = ws + o; o += (size_t)Bn * HW0;
    float* m21  = ws + o; o += (size_t)Bn * HW0;
    int* icnt   = (int*)(ws + o);                 // [0..2] irr, [3..5] ov
    int* irrl0  = icnt + 16;
    int* irrl1  = irrl0 + IRRCAP;
    int* irrl2  = irrl1 + IRRCAP;
    int* ovl0   = irrl2 + IRRCAP;                 // 2*OVCAP each
    int* ovl1   = ovl0 + 2 * OVCAP;
    int* ovl2   = ovl1 + 2 * OVCAP;

    float* l1 = out;
    float* l2 = l1 + (size_t)Bn * 70 * HW0;
    float* l3 = l2 + (size_t)Bn * 128 * HW1;

    (void)hipMemsetAsync(icnt, 0, 16 * sizeof(int), stream);

    // 1) metric (both dirs) + L0 irr detection
    metric2irr0_kernel<<<nblk((long long)2 * Bn * HW0), 256, 0, stream>>>(
        img1, img2, fl12, fl21, m12, m21, icnt + 0, irrl0);

    // 2) L1+L2 irr detection
    irr12_kernel<<<nblk((long long)2 * Bn * (HW1 + HW2)), 256, 0, stream>>>(
        fl12, fl21, icnt + 1, irrl1, icnt + 2, irrl2, dy1, dx1, dy2, dx2);

    // 3) all transposes
    TSegs ts;
    const int GT0 = Bn * HW0 / TSPAN, GT1 = Bn * HW1 / TSPAN, GT2 = Bn * HW2 / TSPAN;
    ts.s0[0] = img1; ts.s1[0] = f1_1;    ts.d[0] = nh0a;
    ts.s0[1] = img2; ts.s1[1] = f2_1;    ts.d[1] = nh0b;
    ts.s0[2] = f1_2; ts.s1[2] = nullptr; ts.d[2] = nh1a;
    ts.s0[3] = f2_2; ts.s1[3] = nullptr; ts.d[3] = nh1b;
    ts.s0[4] = f1_3; ts.s1[4] = nullptr; ts.d[4] = nh2a;
    ts.s0[5] = f2_3; ts.s1[5] = nullptr; ts.d[5] = nh2b;
    ts.start[0] = 0;
    ts.start[1] = GT0;
    ts.start[2] = 2 * GT0;
    ts.start[3] = 2 * GT0 + GT1;
    ts.start[4] = 2 * GT0 + 2 * GT1;
    ts.start[5] = 2 * GT0 + 2 * GT1 + GT2;
    ts.start[6] = 2 * GT0 + 2 * GT1 + 2 * GT2;
    transpose_all_kernel<<<ts.start[6], 256, 0, stream>>>(ts);

    // 4-6) gathers (both dirs per level)
    const int GG0 = 2 * Bn * (H0 / 16) * (W0 / 32);   // 1792
    const int GG1 = 2 * Bn * (H1 / 16) * (W1 / 16);   // 896
    const int GG2 = 2 * Bn * (H2 / 16) * (W2 / 16);   // 224
    // L0: 16x32 tile, FULL channel depth per thread, KBT=5 (3 blocks/CU)
    gather_kernel<0, 35, 9, 9, 9, 16, 16, 32, 5, H0, W0><<<GG0, 512, 0, stream>>>(
        (const float4*)nh0a, (const float4*)nh0b, fl12, fl21, m12, m21, alpha,
        icnt + 0, irrl0, icnt + 3, ovl0, l1, 70, 0, 35, 0.f, 0.f, 0.f);
    // L1/L2: validated 16x16 half-split, KBT=8 (4 blocks/CU)
    gather_kernel<1, 64, 16, 8, 8, 8, 16, 16, 8, H1, W1><<<GG1, 512, 0, stream>>>(
        (const float4*)nh1a, (const float4*)nh1b, fl12, fl21, m12, m21, alpha,
        icnt + 1, irrl1, icnt + 4, ovl1, l2, 128, 0, 64, 0.25f, dy1, dx1);
    gather_kernel<1, 96, 24, 12, 12, 8, 16, 16, 8, H2, W2><<<GG2, 512, 0, stream>>>(
        (const float4*)nh2a, (const float4*)nh2b, fl12, fl21, m12, m21, alpha,
        icnt + 2, irrl2, icnt + 5, ovl2, l3, 192, 0, 96, 0.125f, dy2, dx2);
}

// Round 24
// 385.447 us; speedup vs baseline: 1.3940x; 1.3940x over previous
//
#include <hip/hip_runtime.h>
#include <math.h>

namespace {

constexpr int Bn = 4;
constexpr int H0 = 256, W0 = 448;
constexpr int H1 = 128, W1 = 224;
constexpr int H2 = 64,  W2 = 112;
constexpr int HW0 = H0 * W0;
constexpr int HW1 = H1 * W1;
constexpr int HW2 = H2 * W2;
constexpr int IRRCAP = 8192;
constexpr int OVCAP  = 4096;

// np.linspace(-1+1/n, 1-1/n, n, dtype=f32) bit path (backwarp side; validated).
__device__ inline float lin_ac_f32(int i, int n) {
    if (i == n - 1) return (float)(1.0 - 1.0 / (double)n);
    double start = -1.0 + 1.0 / (double)n;
    double step  = (2.0 - 2.0 / (double)n) / (double)(n - 1);
    return (float)(start + (double)i * step);
}

// jax-f32 linspace bit path + endpoint forcing (validated round 6).
__device__ inline void ac32_iota(int i, int n_in, int n_out, float delta,
                                 int& i0, int& i1, float& fr) {
    float v = (i == n_out - 1) ? (float)(n_in - 1) : __fmul_rn(delta, (float)i);
    float f0 = floorf(v);
    i0 = (int)f0;
    i1 = min(i0 + 1, n_in - 1);
    fr = __fsub_rn(v, f0);
}

// Unfused pinned f32 bilinear (validated round 6).
__device__ inline float bilerp32(const float* __restrict__ s, int Win,
                                 int y0, int y1, int x0, int x1,
                                 float wy, float wx) {
    float a = s[y0 * Win + x0], b = s[y1 * Win + x0];
    float c = s[y0 * Win + x1], d = s[y1 * Win + x1];
    float omwy = __fsub_rn(1.0f, wy), omwx = __fsub_rn(1.0f, wx);
    float r0 = __fadd_rn(__fmul_rn(a, omwy), __fmul_rn(b, wy));
    float r1 = __fadd_rn(__fmul_rn(c, omwy), __fmul_rn(d, wy));
    return __fadd_rn(__fmul_rn(r0, omwx), __fmul_rn(r1, wx));
}

// chunked XCD swizzle (grid divisible by 8)
__device__ inline int swz_block(int bid, int nblk) {
    int cpx = nblk >> 3;
    return (bid & 7) * cpx + (bid >> 3);
}

// ---------------------------------------------------------------------------
// Tap geometry — EXACT round-6/R16 bit paths (validated).
// ---------------------------------------------------------------------------
template<int LVL, int D>
struct Geo {
    int   tx[4], ty[4];
    float tw[4];
    float gx, gy;
    bool  reg;
    int   ry0, ry1, rx0, rx1;
    float wy, wx;
};

template<int LVL, int D>
__device__ inline Geo<LVL, D> geom(int x, int y, int b, int h, int w,
                                   const float* __restrict__ flow,
                                   float scale, float dly, float dlx) {
    Geo<LVL, D> g;
    float gx, gy, x0f, y0f, x1f, y1f;
    if constexpr (LVL == 0) {
        const float* fb = flow + (size_t)b * 2 * HW0;
        float fx = 0.5f * fb[y * W0 + x];
        float fy = 0.5f * fb[(size_t)HW0 + y * W0 + x];
        gx = (float)x + fx;
        gy = (float)y + fy;
        x0f = floorf(gx); y0f = floorf(gy);
        x1f = x0f + 1.f;  y1f = y0f + 1.f;
        g.tw[0] = (x1f - gx) * (y1f - gy); g.tw[1] = (gx - x0f) * (y1f - gy);
        g.tw[2] = (x1f - gx) * (gy - y0f); g.tw[3] = (gx - x0f) * (gy - y0f);
    } else {
        ac32_iota(y, H0, h, dly, g.ry0, g.ry1, g.wy);
        ac32_iota(x, W0, w, dlx, g.rx0, g.rx1, g.wx);
        const float* fB = flow + (size_t)b * 2 * HW0;
        float fx = __fmul_rn(bilerp32(fB, W0, g.ry0, g.ry1, g.rx0, g.rx1, g.wy, g.wx), scale);
        float fy = __fmul_rn(bilerp32(fB + (size_t)HW0, W0, g.ry0, g.ry1, g.rx0, g.rx1, g.wy, g.wx), scale);
        gx = __fadd_rn((float)x, fx);
        gy = __fadd_rn((float)y, fy);
        x0f = floorf(gx); y0f = floorf(gy);
        x1f = __fadd_rn(x0f, 1.0f); y1f = __fadd_rn(y0f, 1.0f);
        float dx0 = __fsub_rn(x1f, gx), dx1 = __fsub_rn(gx, x0f);
        float dy0 = __fsub_rn(y1f, gy), dy1 = __fsub_rn(gy, y0f);
        g.tw[0] = __fmul_rn(dx0, dy0); g.tw[1] = __fmul_rn(dx1, dy0);
        g.tw[2] = __fmul_rn(dx0, dy1); g.tw[3] = __fmul_rn(dx1, dy1);
    }
    g.gx = gx; g.gy = gy;
    int x0 = (int)x0f, y0 = (int)y0f;
    g.tx[0] = x0;     g.tx[1] = x0 + 1; g.tx[2] = x0;     g.tx[3] = x0 + 1;
    g.ty[0] = y0;     g.ty[1] = y0;     g.ty[2] = y0 + 1; g.ty[3] = y0 + 1;
    g.reg = (x0 >= x - D) && (x0 + 1 <= x + D) && (y0 >= y - D) && (y0 + 1 <= y + D);
    return g;
}

// ---------------------------------------------------------------------------
// Metric (both dirs) FUSED with L0 irregular detection (validated R19).
// ---------------------------------------------------------------------------
__global__ __launch_bounds__(256) void metric2irr0_kernel(
        const float* __restrict__ img1, const float* __restrict__ img2,
        const float* __restrict__ fl12, const float* __restrict__ fl21,
        float* __restrict__ m12, float* __restrict__ m21,
        int* __restrict__ irrcnt, int* __restrict__ irrlist) {
    int idx = blockIdx.x * 256 + threadIdx.x;
    int total = 2 * Bn * HW0;
    if (idx >= total) return;
    int dir = idx / (Bn * HW0);
    int sub = idx % (Bn * HW0);
    const float* imgA = dir ? img2 : img1;
    const float* imgB = dir ? img1 : img2;
    const float* flow = dir ? fl21 : fl12;
    float* mout = dir ? m21 : m12;

    int x = sub % W0;
    int y = (sub / W0) % H0;
    int b = sub / HW0;

    const float* fb = flow + (size_t)b * 2 * HW0;
    float fx = fb[y * W0 + x];
    float fy = fb[(size_t)HW0 + y * W0 + x];

    const float sxc = (float)(2.0 / (double)(W0 - 1));
    const float syc = (float)(2.0 / (double)(H0 - 1));
    float ggx = __fadd_rn(lin_ac_f32(x, W0), __fmul_rn(fx, sxc));
    float ggy = __fadd_rn(lin_ac_f32(y, H0), __fmul_rn(fy, syc));
    float px = __fmul_rn(__fmul_rn(__fadd_rn(ggx, 1.0f), 0.5f), (float)(W0 - 1));
    float py = __fmul_rn(__fmul_rn(__fadd_rn(ggy, 1.0f), 0.5f), (float)(H0 - 1));

    float x0f = floorf(px), y0f = floorf(py);
    float x1f = x0f + 1.0f, y1f = y0f + 1.0f;
    int x0 = (int)x0f, y0 = (int)y0f, x1 = (int)x1f, y1 = (int)y1f;

    float tw[4] = { (x1f - px) * (y1f - py), (px - x0f) * (y1f - py),
                    (x1f - px) * (py - y0f), (px - x0f) * (py - y0f) };
    int tx[4] = { x0, x1, x0, x1 };
    int ty[4] = { y0, y0, y1, y1 };

    const float* ib = imgB + (size_t)b * 3 * HW0;
    float acc0 = 0.f, acc1 = 0.f, acc2 = 0.f;
#pragma unroll
    for (int t = 0; t < 4; ++t) {
        bool valid = (tx[t] >= 0) && (tx[t] < W0) && (ty[t] >= 0) && (ty[t] < H0);
        int xc = min(max(tx[t], 0), W0 - 1);
        int yc = min(max(ty[t], 0), H0 - 1);
        float ww = valid ? tw[t] : 0.f;
        int off = yc * W0 + xc;
        acc0 += ib[off] * ww;
        acc1 += ib[(size_t)HW0 + off] * ww;
        acc2 += ib[(size_t)2 * HW0 + off] * ww;
    }
    const float* ia = imgA + (size_t)b * 3 * HW0;
    int off = y * W0 + x;
    float m = (fabsf(ia[off] - acc0) +
               fabsf(ia[(size_t)HW0 + off] - acc1) +
               fabsf(ia[(size_t)2 * HW0 + off] - acc2)) * (1.f / 3.f);
    mout[(size_t)b * HW0 + off] = m;

    // ---- L0 irregular detection (D=16 predicate, matches gather) ----
    float fxh = 0.5f * fx;
    float fyh = 0.5f * fy;
    float sgx = (float)x + fxh;
    float sgy = (float)y + fyh;
    int sx0 = (int)floorf(sgx);
    int sy0 = (int)floorf(sgy);
    bool reg = (sx0 >= x - 16) && (sx0 + 1 <= x + 16) &&
               (sy0 >= y - 16) && (sy0 + 1 <= y + 16);
    if (reg) return;
    bool any = (sx0 >= -1) && (sx0 <= W0 - 1) && (sy0 >= -1) && (sy0 <= H0 - 1);
    if (!any) return;
    int pos = atomicAdd(irrcnt, 1);
    if (pos < IRRCAP) irrlist[pos] = (dir << 20) | (b << 18) | (y * W0 + x);
}

// ---------------------------------------------------------------------------
// Irregular detection for L1+L2 (one launch, segmented; validated R19).
// ---------------------------------------------------------------------------
__global__ __launch_bounds__(256) void irr12_kernel(
        const float* __restrict__ fl12, const float* __restrict__ fl21,
        int* __restrict__ irrcnt1, int* __restrict__ irrlist1,
        int* __restrict__ irrcnt2, int* __restrict__ irrlist2,
        float dy1v, float dx1v, float dy2v, float dx2v) {
    int idx = blockIdx.x * 256 + threadIdx.x;
    const int n1 = 2 * Bn * HW1;
    const int n2 = 2 * Bn * HW2;
    if (idx >= n1 + n2) return;
    int lvl2 = (idx >= n1);
    int sub2 = lvl2 ? (idx - n1) : idx;
    int h = lvl2 ? H2 : H1, w = lvl2 ? W2 : W1;
    float scale = lvl2 ? 0.125f : 0.25f;
    float dly = lvl2 ? dy2v : dy1v, dlx = lvl2 ? dx2v : dx1v;
    int* cnt = lvl2 ? irrcnt2 : irrcnt1;
    int* list = lvl2 ? irrlist2 : irrlist1;

    int hw = h * w;
    int dir = sub2 / (Bn * hw);
    int sub = sub2 % (Bn * hw);
    const float* flow = dir ? fl21 : fl12;
    int x = sub % w, y = (sub / w) % h, b = sub / hw;

    Geo<1, 8> g = geom<1, 8>(x, y, b, h, w, flow, scale, dly, dlx);
    if (g.reg) return;
    bool any = false;
#pragma unroll
    for (int t = 0; t < 4; ++t)
        any = any || ((g.tx[t] >= 0) && (g.tx[t] < w) && (g.ty[t] >= 0) && (g.ty[t] < h));
    if (!any) return;
    int pos = atomicAdd(cnt, 1);
    if (pos < IRRCAP) list[pos] = (dir << 20) | (b << 18) | (y * w + x);
}

// ---------------------------------------------------------------------------
// Transpose NCHW->NHWC (validated R21): compile-time CH, float4 reads,
// SPAN=64, padded LDS stride.
// ---------------------------------------------------------------------------
constexpr int TSPAN = 64;

template<int CH, int C0, int C1>
__device__ inline void tbody(const float* __restrict__ s0,
                             const float* __restrict__ s1,
                             float* __restrict__ dst, int HW, int gp,
                             float* __restrict__ lds) {
    constexpr int S = CH + 1;
    constexpr int PV = TSPAN / 4;
    constexpr int CT = C0 + C1;
    int b = gp / HW, p0 = gp % HW;
    int tid = threadIdx.x;

#pragma unroll 4
    for (int i = tid; i < CH * PV; i += 256) {
        int c = i / PV;
        int pv = (i % PV) * 4;
        float4 v = { 0.f, 0.f, 0.f, 0.f };
        if (c < C0)
            v = *(const float4*)(s0 + ((size_t)b * C0 + c) * HW + p0 + pv);
        else if (c < CT)
            v = *(const float4*)(s1 + ((size_t)b * C1 + (c - C0)) * HW + p0 + pv);
        lds[(pv + 0) * S + c] = v.x;
        lds[(pv + 1) * S + c] = v.y;
        lds[(pv + 2) * S + c] = v.z;
        lds[(pv + 3) * S + c] = v.w;
    }
    __syncthreads();

    constexpr int N4 = TSPAN * CH / 4;
    float4* d4 = (float4*)(dst + (size_t)gp * CH);
#pragma unroll 4
    for (int i = tid; i < N4; i += 256) {
        int j = i * 4;
        int p = j / CH, c = j % CH;
        float4 q = { lds[p * S + c], lds[p * S + c + 1],
                     lds[p * S + c + 2], lds[p * S + c + 3] };
        d4[i] = q;
    }
}

struct TSegs {
    const float* s0[6];
    const float* s1[6];
    float*       d[6];
    int start[7];
};

__global__ __launch_bounds__(256) void transpose_all_kernel(TSegs ts) {
    __shared__ float lds[TSPAN * 97];
    int bid = blockIdx.x;
    int k = 0;
#pragma unroll
    for (int i = 1; i < 6; ++i) if (bid >= ts.start[i]) k = i;
    int gp = (bid - ts.start[k]) * TSPAN;
    switch (k) {
        case 0: tbody<36, 3, 32>(ts.s0[0], ts.s1[0], ts.d[0], HW0, gp, lds); break;
        case 1: tbody<36, 3, 32>(ts.s0[1], ts.s1[1], ts.d[1], HW0, gp, lds); break;
        case 2: tbody<64, 64, 0>(ts.s0[2], ts.s1[2], ts.d[2], HW1, gp, lds); break;
        case 3: tbody<64, 64, 0>(ts.s0[3], ts.s1[3], ts.d[3], HW1, gp, lds); break;
        case 4: tbody<96, 96, 0>(ts.s0[4], ts.s1[4], ts.d[4], HW2, gp, lds); break;
        case 5: tbody<96, 96, 0>(ts.s0[5], ts.s1[5], ts.d[5], HW2, gp, lds); break;
    }
}

// ---------------------------------------------------------------------------
// Full-recompute gather (overflow path only; rare). Validated R16 body.
// ---------------------------------------------------------------------------
template<int LVL, int D, int H, int W, int CBT4, int NVM>
__device__ inline void gather_one(int sidx, int b, int px, int py, int voff, int nv,
        const float* __restrict__ flow, const float* __restrict__ met, float a,
        float scale, float dly, float dlx, const float4* __restrict__ nhwc,
        float (&ax)[NVM], float (&ay)[NVM], float (&az)[NVM], float (&aw)[NVM],
        float& wacc) {
    int sx = sidx % W, sy = sidx / W;
    Geo<LVL, D> g = geom<LVL, D>(sx, sy, b, H, W, flow, scale, dly, dlx);
    int ddx = px - g.tx[0], ddy = py - g.ty[0];
    if (((unsigned)ddx > 1u) || ((unsigned)ddy > 1u)) return;
    int t = ddy * 2 + ddx;
    float wgt;
    if constexpr (LVL == 0) wgt = expf(a * met[(size_t)b * HW0 + sy * W0 + sx]);
    else {
        float m = bilerp32(met + (size_t)b * HW0, W0, g.ry0, g.ry1, g.rx0, g.rx1, g.wy, g.wx);
        wgt = expf(__fmul_rn(a, m));
    }
    float tw = (t == 0) ? g.tw[0] : (t == 1) ? g.tw[1] : (t == 2) ? g.tw[2] : g.tw[3];
    float twv = (LVL == 0) ? tw * wgt : __fmul_rn(wgt, tw);
    wacc += twv;
    const float4* vp = nhwc + ((size_t)b * (H * W) + sidx) * CBT4 + voff;
#pragma unroll
    for (int vi = 0; vi < NVM; ++vi) {
        if (vi >= nv) break;
        float4 q = vp[vi];
        if constexpr (LVL == 0) {
            ax[vi] += q.x * twv; ay[vi] += q.y * twv;
            az[vi] += q.z * twv; aw[vi] += q.w * twv;
        } else {
            ax[vi] += __fmul_rn(__fmul_rn(q.x, wgt), tw);
            ay[vi] += __fmul_rn(__fmul_rn(q.y, wgt), tw);
            az[vi] += __fmul_rn(__fmul_rn(q.z, wgt), tw);
            aw[vi] += __fmul_rn(__fmul_rn(q.w, wgt), tw);
        }
    }
}

// ---------------------------------------------------------------------------
// Gather (validated R22 configuration — best measured: 386us total).
// L0: 16x32 tile FULL-depth KBT=6; L1/L2: 16x16 half-split KBT=10.
// ---------------------------------------------------------------------------
template<int LVL, int CREAL, int CBT4, int NV0, int NV1, int D, int TH, int TW,
         int KBT, int H, int W>
__global__ __launch_bounds__(512) void gather_kernel(
        const float4* __restrict__ nhwcA, const float4* __restrict__ nhwcB,
        const float* __restrict__ fl12, const float* __restrict__ fl21,
        const float* __restrict__ m12, const float* __restrict__ m21,
        const float* __restrict__ alphap,
        const int* __restrict__ irrn_p, const int* __restrict__ irrlist,
        int* __restrict__ ovn_p, int* __restrict__ ovlist,
        float* __restrict__ outp, int Cout, int cbase0, int cbase1,
        float scale, float dly, float dlx) {
    constexpr int NPIX = TH * TW;
    constexpr bool FULL = (NPIX == 512);
    constexpr int NBX = TW + 1, NB = NBX * (TH + 1);
    constexpr int NVM = FULL ? CBT4 : ((NV0 > NV1) ? NV0 : NV1);
    constexpr int HW_ = H * W;
    __shared__ int   bcnt[NB];
    __shared__ int   bsidx[NB * KBT];
    __shared__ float bgx[NB * KBT], bgy[NB * KBT], bwgt[NB * KBT];
    __shared__ int s_irrn, s_ovn;

    const int tilesX = W / TW, tilesY = H / TH;
    int s = swz_block(blockIdx.x, gridDim.x);
    int tpb = tilesX * tilesY;
    int dir = s / (Bn * tpb);
    int rem = s % (Bn * tpb);
    int b = rem / tpb, r = rem % tpb;
    int ty0 = (r / tilesX) * TH, tx0 = (r % tilesX) * TW;
    int tid = threadIdx.x;

    const float* flow = dir ? fl21 : fl12;
    const float* met  = dir ? m21 : m12;
    const float4* nhwc = dir ? nhwcB : nhwcA;
    int cbase = dir ? cbase1 : cbase0;

    for (int i = tid; i < NB; i += 512) bcnt[i] = 0;
    if (tid == 0) s_irrn = irrn_p[0];
    __syncthreads();

    float a = alphap[0];

    // ---- phase 1a: window scan; bin by destination cell ----
    constexpr int WH = TH + 2 * D, WW2 = TW + 2 * D;
    int wy0 = ty0 - D, wx0 = tx0 - D;
    for (int i = tid; i < WH * WW2; i += 512) {
        int sy = wy0 + i / WW2, sx = wx0 + i % WW2;
        if (sy < 0 || sy >= H || sx < 0 || sx >= W) continue;
        Geo<LVL, D> g = geom<LVL, D>(sx, sy, b, H, W, flow, scale, dly, dlx);
        if (!g.reg) continue;
        int cx = g.tx[0], cy = g.ty[0];
        if (cx < tx0 - 1 || cx > tx0 + TW - 1 || cy < ty0 - 1 || cy > ty0 + TH - 1) continue;
        float wgt;
        if constexpr (LVL == 0) wgt = expf(a * met[(size_t)b * HW0 + sy * W0 + sx]);
        else {
            float m = bilerp32(met + (size_t)b * HW0, W0, g.ry0, g.ry1, g.rx0, g.rx1, g.wy, g.wx);
            wgt = expf(__fmul_rn(a, m));
        }
        int bin = (cy - (ty0 - 1)) * NBX + (cx - (tx0 - 1));
        int pos = atomicAdd(&bcnt[bin], 1);
        int sidx = sy * W + sx;
        if (pos < KBT) {
            int e = bin * KBT + pos;
            bsidx[e] = sidx; bgx[e] = g.gx; bgy[e] = g.gy; bwgt[e] = wgt;
        } else {
            int p2 = atomicAdd(ovn_p, 1);
            if (p2 < OVCAP) { atomicExch(&ovlist[2 * p2], s); atomicExch(&ovlist[2 * p2 + 1], sidx); }
        }
    }
    // ---- phase 1b: irregular sources (dir+batch filtered) ----
    int ni = min(s_irrn, IRRCAP);
    for (int i = tid; i < ni; i += 512) {
        int e0 = irrlist[i];
        if ((e0 >> 20) != dir) continue;
        if (((e0 >> 18) & 3) != b) continue;
        int sidx = e0 & ((1 << 18) - 1);
        int sx = sidx % W, sy = sidx / W;
        Geo<LVL, D> g = geom<LVL, D>(sx, sy, b, H, W, flow, scale, dly, dlx);
        int cx = g.tx[0], cy = g.ty[0];
        if (cx < tx0 - 1 || cx > tx0 + TW - 1 || cy < ty0 - 1 || cy > ty0 + TH - 1) continue;
        float wgt;
        if constexpr (LVL == 0) wgt = expf(a * met[(size_t)b * HW0 + sy * W0 + sx]);
        else {
            float m = bilerp32(met + (size_t)b * HW0, W0, g.ry0, g.ry1, g.rx0, g.rx1, g.wy, g.wx);
            wgt = expf(__fmul_rn(a, m));
        }
        int bin = (cy - (ty0 - 1)) * NBX + (cx - (tx0 - 1));
        int pos = atomicAdd(&bcnt[bin], 1);
        if (pos < KBT) {
            int e = bin * KBT + pos;
            bsidx[e] = sidx; bgx[e] = g.gx; bgy[e] = g.gy; bwgt[e] = wgt;
        } else {
            int p2 = atomicAdd(ovn_p, 1);
            if (p2 < OVCAP) { atomicExch(&ovlist[2 * p2], s); atomicExch(&ovlist[2 * p2 + 1], sidx); }
        }
    }
    __syncthreads();
    if (tid == 0) s_ovn = atomicAdd(ovn_p, 0);
    __syncthreads();

    // ---- phase 2: register gather ----
    int pixel, voff, nv;
    if constexpr (FULL) {
        pixel = tid; voff = 0; nv = CBT4;
    } else {
        pixel = tid & 255;
        int half = tid >> 8;
        voff = half ? NV0 : 0;
        nv = half ? NV1 : NV0;
    }
    int px = tx0 + (pixel % TW), py = ty0 + (pixel / TW);
    const float4* nbp = nhwc + (size_t)b * HW_ * CBT4 + voff;
    float ax[NVM], ay[NVM], az[NVM], aw[NVM];
#pragma unroll
    for (int vi = 0; vi < NVM; ++vi) { ax[vi] = 0.f; ay[vi] = 0.f; az[vi] = 0.f; aw[vi] = 0.f; }
    float wacc = 0.f;

#pragma unroll
    for (int cyi = 0; cyi < 2; ++cyi)
#pragma unroll
    for (int cxi = 0; cxi < 2; ++cxi) {
        const int t = (1 - cyi) * 2 + (1 - cxi);
        int lc = (py - ty0 + cyi) * NBX + (px - tx0 + cxi);
        int n = min(bcnt[lc], KBT);
        for (int j = 0; j < n; ++j) {
            int e = lc * KBT + j;
            float gx = bgx[e], gy = bgy[e], wgt = bwgt[e];
            float x0f = floorf(gx), y0f = floorf(gy);
            float tw;
            if constexpr (LVL == 0) {
                float x1f = x0f + 1.f, y1f = y0f + 1.f;
                tw = (t == 0) ? (x1f - gx) * (y1f - gy)
                   : (t == 1) ? (gx - x0f) * (y1f - gy)
                   : (t == 2) ? (x1f - gx) * (gy - y0f)
                              : (gx - x0f) * (gy - y0f);
            } else {
                float x1f = __fadd_rn(x0f, 1.0f), y1f = __fadd_rn(y0f, 1.0f);
                float dx0 = __fsub_rn(x1f, gx), dx1 = __fsub_rn(gx, x0f);
                float dy0 = __fsub_rn(y1f, gy), dy1 = __fsub_rn(gy, y0f);
                tw = (t == 0) ? __fmul_rn(dx0, dy0)
                   : (t == 1) ? __fmul_rn(dx1, dy0)
                   : (t == 2) ? __fmul_rn(dx0, dy1)
                              : __fmul_rn(dx1, dy1);
            }
            const float4* vp = nbp + (size_t)bsidx[e] * CBT4;
            if constexpr (LVL == 0) {
                float twv = tw * wgt;
                wacc += twv;
#pragma unroll
                for (int vi = 0; vi < NVM; ++vi) {
                    if (vi >= nv) break;
                    float4 q = vp[vi];
                    ax[vi] += q.x * twv; ay[vi] += q.y * twv;
                    az[vi] += q.z * twv; aw[vi] += q.w * twv;
                }
            } else {
                wacc += __fmul_rn(wgt, tw);
#pragma unroll
                for (int vi = 0; vi < NVM; ++vi) {
                    if (vi >= nv) break;
                    float4 q = vp[vi];
                    ax[vi] += __fmul_rn(__fmul_rn(q.x, wgt), tw);
                    ay[vi] += __fmul_rn(__fmul_rn(q.y, wgt), tw);
                    az[vi] += __fmul_rn(__fmul_rn(q.z, wgt), tw);
                    aw[vi] += __fmul_rn(__fmul_rn(q.w, wgt), tw);
                }
            }
        }
    }
    // overflow entries (expected ~0 at validated KBT)
    int novr = min(s_ovn, OVCAP);
    for (int j = 0; j < novr; ++j) {
        if (atomicAdd(&ovlist[2 * j], 0) != s) continue;
        int sidx = atomicAdd(&ovlist[2 * j + 1], 0);
        gather_one<LVL, D, H, W, CBT4, NVM>(sidx, b, px, py, voff, nv,
            flow, met, a, scale, dly, dlx, nhwc, ax, ay, az, aw, wacc);
    }

    float denom = wacc + 1e-7f;
    size_t obase = ((size_t)b * Cout + cbase) * HW_ + (py * W + px);
#pragma unroll
    for (int vi = 0; vi < NVM; ++vi) {
        if (vi >= nv) break;
        int c0 = (voff + vi) * 4;
        if (c0 + 0 < CREAL) outp[obase + (size_t)(c0 + 0) * HW_] = ax[vi] / denom;
        if (c0 + 1 < CREAL) outp[obase + (size_t)(c0 + 1) * HW_] = ay[vi] / denom;
        if (c0 + 2 < CREAL) outp[obase + (size_t)(c0 + 2) * HW_] = az[vi] / denom;
        if (c0 + 3 < CREAL) outp[obase + (size_t)(c0 + 3) * HW_] = aw[vi] / denom;
    }
}

inline int nblk(long long n) { return (int)((n + 255) / 256); }

} // namespace

extern "C" void kernel_launch(void* const* d_in, const int* in_sizes, int n_in,
                              void* d_out, int out_size, void* d_ws, size_t ws_size,
                              hipStream_t stream) {
    const float* img1 = (const float*)d_in[0];
    const float* img2 = (const float*)d_in[1];
    const float* f1_1 = (const float*)d_in[2];
    const float* f1_2 = (const float*)d_in[3];
    const float* f1_3 = (const float*)d_in[4];
    const float* f2_1 = (const float*)d_in[5];
    const float* f2_2 = (const float*)d_in[6];
    const float* f2_3 = (const float*)d_in[7];
    const float* fl12 = (const float*)d_in[8];
    const float* fl21 = (const float*)d_in[9];
    const float* alpha = (const float*)d_in[10];
    float* out = (float*)d_out;

    const float dy1 = (float)(H0 - 1) / (float)(H1 - 1);
    const float dx1 = (float)(W0 - 1) / (float)(W1 - 1);
    const float dy2 = (float)(H0 - 1) / (float)(H2 - 1);
    const float dx2 = (float)(W0 - 1) / (float)(W2 - 1);

    // ---- workspace layout (NHWC buffers first, 16B-aligned) ----
    float* ws = (float*)d_ws;
    size_t o = 0;
    float* nh0a = ws + o; o += (size_t)Bn * HW0 * 36;
    float* nh0b = ws + o; o += (size_t)Bn * HW0 * 36;
    float* nh1a = ws + o; o += (size_t)Bn * HW1 * 64;
    float* nh1b = ws + o; o += (size_t)Bn * HW1 * 64;
    float* nh2a = ws + o; o += (size_t)Bn * HW2 * 96;
    float* nh2b = ws + o; o += (size_t)Bn * HW2 * 96;
    float* m12  = ws + o; o += (size_t)Bn * HW0;
    float* m21  = ws + o; o += (size_t)Bn * HW0;
    int* icnt   = (int*)(ws + o);                 // [0..2] irr, [3..5] ov
    int* irrl0  = icnt + 16;
    int* irrl1  = irrl0 + IRRCAP;
    int* irrl2  = irrl1 + IRRCAP;
    int* ovl0   = irrl2 + IRRCAP;                 // 2*OVCAP each
    int* ovl1   = ovl0 + 2 * OVCAP;
    int* ovl2   = ovl1 + 2 * OVCAP;

    float* l1 = out;
    float* l2 = l1 + (size_t)Bn * 70 * HW0;
    float* l3 = l2 + (size_t)Bn * 128 * HW1;

    (void)hipMemsetAsync(icnt, 0, 16 * sizeof(int), stream);

    // 1) metric (both dirs) + L0 irr detection
    metric2irr0_kernel<<<nblk((long long)2 * Bn * HW0), 256, 0, stream>>>(
        img1, img2, fl12, fl21, m12, m21, icnt + 0, irrl0);

    // 2) L1+L2 irr detection
    irr12_kernel<<<nblk((long long)2 * Bn * (HW1 + HW2)), 256, 0, stream>>>(
        fl12, fl21, icnt + 1, irrl1, icnt + 2, irrl2, dy1, dx1, dy2, dx2);

    // 3) all transposes
    TSegs ts;
    const int GT0 = Bn * HW0 / TSPAN, GT1 = Bn * HW1 / TSPAN, GT2 = Bn * HW2 / TSPAN;
    ts.s0[0] = img1; ts.s1[0] = f1_1;    ts.d[0] = nh0a;
    ts.s0[1] = img2; ts.s1[1] = f2_1;    ts.d[1] = nh0b;
    ts.s0[2] = f1_2; ts.s1[2] = nullptr; ts.d[2] = nh1a;
    ts.s0[3] = f2_2; ts.s1[3] = nullptr; ts.d[3] = nh1b;
    ts.s0[4] = f1_3; ts.s1[4] = nullptr; ts.d[4] = nh2a;
    ts.s0[5] = f2_3; ts.s1[5] = nullptr; ts.d[5] = nh2b;
    ts.start[0] = 0;
    ts.start[1] = GT0;
    ts.start[2] = 2 * GT0;
    ts.start[3] = 2 * GT0 + GT1;
    ts.start[4] = 2 * GT0 + 2 * GT1;
    ts.start[5] = 2 * GT0 + 2 * GT1 + GT2;
    ts.start[6] = 2 * GT0 + 2 * GT1 + 2 * GT2;
    transpose_all_kernel<<<ts.start[6], 256, 0, stream>>>(ts);

    // 4-6) gathers (both dirs per level) — validated R22 configs
    const int GG0 = 2 * Bn * (H0 / 16) * (W0 / 32);   // 1792
    const int GG1 = 2 * Bn * (H1 / 16) * (W1 / 16);   // 896
    const int GG2 = 2 * Bn * (H2 / 16) * (W2 / 16);   // 224
    gather_kernel<0, 35, 9, 9, 9, 16, 16, 32, 6, H0, W0><<<GG0, 512, 0, stream>>>(
        (const float4*)nh0a, (const float4*)nh0b, fl12, fl21, m12, m21, alpha,
        icnt + 0, irrl0, icnt + 3, ovl0, l1, 70, 0, 35, 0.f, 0.f, 0.f);
    gather_kernel<1, 64, 16, 8, 8, 8, 16, 16, 10, H1, W1><<<GG1, 512, 0, stream>>>(
        (const float4*)nh1a, (const float4*)nh1b, fl12, fl21, m12, m21, alpha,
        icnt + 1, irrl1, icnt + 4, ovl1, l2, 128, 0, 64, 0.25f, dy1, dx1);
    gather_kernel<1, 96, 24, 12, 12, 8, 16, 16, 10, H2, W2><<<GG2, 512, 0, stream>>>(
        (const float4*)nh2a, (const float4*)nh2b, fl12, fl21, m12, m21, alpha,
        icnt + 2, irrl2, icnt + 5, ovl2, l3, 192, 0, 96, 0.125f, dy2, dx2);
}